// Round 1
// 2920.498 us; speedup vs baseline: 1.4109x; 1.4109x over previous
//
#include <hip/hip_runtime.h>
#include <math.h>

#define BATCH 32
#define NF 128
#define FLAT 784
#define HID2 392
#define EO 64
#define FIN 8192
#define FHID 4096
#define NOUT 53

// ---------------------------------------------------------------------------
// Conv3x3 (SAME) + ReLU + MaxPool2x2, multi-output-channel blocked.
// Each thread: one pooled output pixel for COB consecutive output channels.
// The 4x4 input patch is loaded once per ci and reused across COB channels
// (288 FMAs per 16 global loads at COB=8, vs 36 in the naive version).
// Weights staged in LDS padded to 12 floats/(ci,co) so they read back as
// ds_read_b128 pairs. grid: (ceil(HOUT/16), ceil(HOUT/16), B*CO/COB),
// block: (16,16).
// ---------------------------------------------------------------------------
template<int CI, int COB>
__global__ __launch_bounds__(256) void conv_relu_pool_mc(
        const float* __restrict__ in,
        const float* __restrict__ wt,
        const float* __restrict__ bias,
        float* __restrict__ out,
        int HIN, int CO) {
    const int HOUT = HIN >> 1;
    const int nb = CO / COB;
    int bz = blockIdx.z;
    int cb = bz % nb;
    int b  = bz / nb;
    int co0 = cb * COB;

    extern __shared__ float ws_[];          // [CI][COB][12] padded weights
    int tid = threadIdx.y * 16 + threadIdx.x;
    for (int i = tid; i < CI * COB * 9; i += 256) {
        int ci  = i / (COB * 9);
        int rem = i % (COB * 9);
        int u   = rem / 9, k = rem % 9;
        ws_[(ci * COB + u) * 12 + k] = wt[((long)(co0 + u) * CI + ci) * 9 + k];
    }
    __syncthreads();

    int px = blockIdx.x * 16 + threadIdx.x;
    int py = blockIdx.y * 16 + threadIdx.y;
    if (px >= HOUT || py >= HOUT) return;

    int x0 = 2 * px - 1;                    // 4x4 input patch origin
    int y0 = 2 * py - 1;
    const float* inb = in + (long)b * CI * HIN * HIN;

    float acc[COB][4];
    #pragma unroll
    for (int u = 0; u < COB; u++) {
        float bv = bias[co0 + u];
        acc[u][0] = bv; acc[u][1] = bv; acc[u][2] = bv; acc[u][3] = bv;
    }
    const bool interior = (x0 >= 0) & (y0 >= 0) & (x0 + 3 < HIN) & (y0 + 3 < HIN);

    #pragma unroll 2
    for (int ci = 0; ci < CI; ci++) {
        const float* ip = inb + (long)ci * HIN * HIN + (long)y0 * HIN + x0;
        float p[4][4];
        if (interior) {
            #pragma unroll
            for (int r = 0; r < 4; r++)
                #pragma unroll
                for (int c = 0; c < 4; c++)
                    p[r][c] = ip[r * HIN + c];
        } else {
            #pragma unroll
            for (int r = 0; r < 4; r++) {
                int yy = y0 + r;
                bool yok = (yy >= 0) & (yy < HIN);
                #pragma unroll
                for (int c = 0; c < 4; c++) {
                    int xx = x0 + c;
                    p[r][c] = (yok & (xx >= 0) & (xx < HIN))
                              ? inb[(long)ci * HIN * HIN + (long)yy * HIN + xx] : 0.f;
                }
            }
        }
        const float* wc = ws_ + (long)ci * COB * 12;
        #pragma unroll
        for (int u = 0; u < COB; u++) {
            const float* wp = wc + u * 12;
            float4 wv0 = *reinterpret_cast<const float4*>(wp);
            float4 wv1 = *reinterpret_cast<const float4*>(wp + 4);
            float w8   = wp[8];
            float wk[9] = {wv0.x, wv0.y, wv0.z, wv0.w,
                           wv1.x, wv1.y, wv1.z, wv1.w, w8};
            #pragma unroll
            for (int ky = 0; ky < 3; ky++)
                #pragma unroll
                for (int kx = 0; kx < 3; kx++) {
                    float wv = wk[ky * 3 + kx];
                    acc[u][0] = fmaf(p[ky][kx],         wv, acc[u][0]);
                    acc[u][1] = fmaf(p[ky][kx + 1],     wv, acc[u][1]);
                    acc[u][2] = fmaf(p[ky + 1][kx],     wv, acc[u][2]);
                    acc[u][3] = fmaf(p[ky + 1][kx + 1], wv, acc[u][3]);
                }
        }
    }
    #pragma unroll
    for (int u = 0; u < COB; u++) {
        float m = fmaxf(fmaxf(acc[u][0], acc[u][1]), fmaxf(acc[u][2], acc[u][3]));
        out[(((long)(b * CO + co0 + u)) * HOUT + py) * HOUT + px] = fmaxf(m, 0.f);
    }
}

// ---------------------------------------------------------------------------
// Attention: s[b,n] = dot(f[b,n,:], wa) + ba  -- one wave per (b,n)
// ---------------------------------------------------------------------------
__global__ void att_dot(const float* __restrict__ f, const float* __restrict__ wa,
                        const float* __restrict__ ba, float* __restrict__ s) {
    int bn = blockIdx.x;
    int lane = threadIdx.x;
    const float* row = f + (long)bn * FLAT;
    float acc = 0.f;
    for (int k = lane; k < FLAT; k += 64) acc += row[k] * wa[k];
    #pragma unroll
    for (int off = 32; off > 0; off >>= 1) acc += __shfl_down(acc, off);
    if (lane == 0) s[bn] = acc + ba[0];
}

// softmax over n (128) per b -- grid: B, block: 128
__global__ void att_softmax(const float* __restrict__ s, float* __restrict__ att) {
    int b = blockIdx.x;
    int n = threadIdx.x;
    float v = s[b * NF + n];
    __shared__ float red[NF];
    red[n] = v; __syncthreads();
    for (int off = 64; off > 0; off >>= 1) {
        if (n < off) red[n] = fmaxf(red[n], red[n + off]);
        __syncthreads();
    }
    float m = red[0];
    __syncthreads();
    float e = expf(v - m);
    red[n] = e; __syncthreads();
    for (int off = 64; off > 0; off >>= 1) {
        if (n < off) red[n] += red[n + off];
        __syncthreads();
    }
    att[b * NF + n] = e / red[0];
}

// ---------------------------------------------------------------------------
// Batched expert GEMM: out[b,n,c] = relu( sum_k A[b,n,k]*W[n,k,c] + bias[n,c] )
// optional per-(b,n) input scale (att). grid: (ceil(N/64), NF), block: 256
// thread t: col = c0 + (t&63), rows (t>>6)*8 .. +7
// ---------------------------------------------------------------------------
__global__ void expert_gemm(const float* __restrict__ A, const float* __restrict__ W,
                            const float* __restrict__ bias, const float* __restrict__ att,
                            float* __restrict__ out, int K, int N) {
    int n  = blockIdx.y;
    int t  = threadIdx.x;
    int c  = blockIdx.x * 64 + (t & 63);
    int rg = t >> 6;
    __shared__ float As[32][64];
    float acc[8];
    #pragma unroll
    for (int j = 0; j < 8; j++) acc[j] = 0.f;
    const float* Wn = W + (long)n * K * N;

    for (int k0 = 0; k0 < K; k0 += 64) {
        int kt = K - k0; if (kt > 64) kt = 64;
        __syncthreads();
        for (int i = t; i < 32 * 64; i += 256) {
            int r = i >> 6, kk = i & 63;
            float v = 0.f;
            if (kk < kt) {
                v = A[(((long)r) * NF + n) * K + k0 + kk];
                if (att) v *= att[r * NF + n];
            }
            As[r][kk] = v;
        }
        __syncthreads();
        if (c < N) {
            for (int kk = 0; kk < kt; kk++) {
                float w = Wn[(long)(k0 + kk) * N + c];
                #pragma unroll
                for (int j = 0; j < 8; j++)
                    acc[j] = fmaf(As[rg * 8 + j][kk], w, acc[j]);
            }
        }
    }
    if (c < N) {
        float bv = bias[(long)n * N + c];
        #pragma unroll
        for (int j = 0; j < 8; j++) {
            float v = fmaxf(acc[j] + bv, 0.f);
            out[(((long)(rg * 8 + j)) * NF + n) * N + c] = v;
        }
    }
}

// ---------------------------------------------------------------------------
// Head GEMM with split-K partials: part[sk,r,c] = sum_{k in chunk} A[r,k]*W[k,c]
// A: [32,K] contiguous. grid: (N/64, SK), block 256. K%(SK*64)==0, N%64==0.
// ---------------------------------------------------------------------------
template<int SK>
__global__ void head_gemm(const float* __restrict__ A, const float* __restrict__ W,
                          float* __restrict__ part, int K, int N) {
    int sk = blockIdx.y;
    int t  = threadIdx.x;
    int c  = blockIdx.x * 64 + (t & 63);
    int rg = t >> 6;
    int kchunk = K / SK;
    int kbeg = sk * kchunk;
    __shared__ float As[32][64];
    float acc[8];
    #pragma unroll
    for (int j = 0; j < 8; j++) acc[j] = 0.f;

    for (int k0 = kbeg; k0 < kbeg + kchunk; k0 += 64) {
        __syncthreads();
        for (int i = t; i < 2048; i += 256) {
            int r = i >> 6, kk = i & 63;
            As[r][kk] = A[(long)r * K + k0 + kk];
        }
        __syncthreads();
        for (int kk = 0; kk < 64; kk++) {
            float w = W[(long)(k0 + kk) * N + c];
            #pragma unroll
            for (int j = 0; j < 8; j++)
                acc[j] = fmaf(As[rg * 8 + j][kk], w, acc[j]);
        }
    }
    #pragma unroll
    for (int j = 0; j < 8; j++)
        part[((long)sk * 32 + rg * 8 + j) * N + c] = acc[j];
}

template<int SK>
__global__ void head_epilogue(const float* __restrict__ part, const float* __restrict__ bias,
                              float* __restrict__ out, int N, int do_relu) {
    int idx = blockIdx.x * 256 + threadIdx.x;
    if (idx >= 32 * N) return;
    int r = idx / N, c = idx % N;
    float acc = bias[c];
    #pragma unroll
    for (int s = 0; s < SK; s++) acc += part[((long)s * 32 + r) * N + c];
    if (do_relu) acc = fmaxf(acc, 0.f);
    out[idx] = acc;
}

// Final tiny GEMM: out[r,c] = sum_k g2[r,k]*fw3[k,c] + fb3[c]; grid 53, block 256
__global__ void head3(const float* __restrict__ A, const float* __restrict__ W,
                      const float* __restrict__ bias, float* __restrict__ out) {
    int c  = blockIdx.x;
    int t  = threadIdx.x;
    int r  = t & 31;
    int kg = t >> 5;                 // 0..7
    float acc = 0.f;
    for (int k = kg; k < FHID; k += 8)
        acc += A[(long)r * FHID + k] * W[(long)k * NOUT + c];
    __shared__ float red[256];
    red[t] = acc;
    __syncthreads();
    for (int off = 4; off >= 1; off >>= 1) {
        if (kg < off) red[t] += red[t + off * 32];
        __syncthreads();
    }
    if (kg == 0) out[(long)r * NOUT + c] = red[r] + bias[c];
}

// ---------------------------------------------------------------------------
extern "C" void kernel_launch(void* const* d_in, const int* in_sizes, int n_in,
                              void* d_out, int out_size, void* d_ws, size_t ws_size,
                              hipStream_t stream) {
    const float* x   = (const float*)d_in[0];
    const float* cw1 = (const float*)d_in[1];
    const float* cb1 = (const float*)d_in[2];
    const float* cw2 = (const float*)d_in[3];
    const float* cb2 = (const float*)d_in[4];
    const float* cw3 = (const float*)d_in[5];
    const float* cb3 = (const float*)d_in[6];
    const float* wa  = (const float*)d_in[7];
    const float* ba  = (const float*)d_in[8];
    const float* ew1 = (const float*)d_in[9];
    const float* eb1 = (const float*)d_in[10];
    const float* ew2 = (const float*)d_in[11];
    const float* eb2 = (const float*)d_in[12];
    const float* ew3 = (const float*)d_in[13];
    const float* eb3 = (const float*)d_in[14];
    const float* fw1 = (const float*)d_in[15];
    const float* fb1 = (const float*)d_in[16];
    const float* fw2 = (const float*)d_in[17];
    const float* fb2 = (const float*)d_in[18];
    const float* fw3 = (const float*)d_in[19];
    const float* fb3 = (const float*)d_in[20];
    float* outp = (float*)d_out;

    // workspace layout (floats), with buffer reuse:
    float* ws = (float*)d_ws;
    float* p1   = ws;                    // 32*32*112*112 = 12,845,056
    float* p2   = p1 + 12845056;         // 32*64*56*56   =  6,422,528
    float* f    = p2 + 6422528;          // 32*128*784    =  3,211,264
    float* sS   = f  + 3211264;          // 4096
    float* attb = sS + 4096;             // 4096
    // p1 dead after conv2 -> reuse for h1; p2 dead after conv3 -> reuse region
    float* h1   = p1;                    // 3,211,264
    float* h2   = p2;                    // 1,605,632
    float* e    = h2 + 1605632;          // 262,144
    float* part = e  + 262144;           // 8*32*8192 = 2,097,152 (reused for head2)
    float* g1   = part + 2097152;        // 262,144
    float* g2   = g1 + 262144;           // 131,072

    // --- CNN feature extractor (COB=8 output channels per block) ---
    conv_relu_pool_mc<3, 8><<<dim3(7, 7, BATCH * (32 / 8)), dim3(16, 16),
                              3 * 8 * 12 * 4, stream>>>(x, cw1, cb1, p1, 224, 32);
    conv_relu_pool_mc<32, 8><<<dim3(4, 4, BATCH * (64 / 8)), dim3(16, 16),
                               32 * 8 * 12 * 4, stream>>>(p1, cw2, cb2, p2, 112, 64);
    conv_relu_pool_mc<64, 8><<<dim3(2, 2, BATCH * (128 / 8)), dim3(16, 16),
                               64 * 8 * 12 * 4, stream>>>(p2, cw3, cb3, f, 56, 128);

    // --- attention over feature maps ---
    att_dot<<<BATCH * NF, 64, 0, stream>>>(f, wa, ba, sS);
    att_softmax<<<BATCH, NF, 0, stream>>>(sS, attb);

    // --- 128 batched experts ---
    expert_gemm<<<dim3((FLAT + 63) / 64, NF), 256, 0, stream>>>(f,  ew1, eb1, attb, h1, FLAT, FLAT);
    expert_gemm<<<dim3((HID2 + 63) / 64, NF), 256, 0, stream>>>(h1, ew2, eb2, nullptr, h2, FLAT, HID2);
    expert_gemm<<<dim3(1, NF),               256, 0, stream>>>(h2, ew3, eb3, nullptr, e, HID2, EO);

    // --- head MLP ---
    head_gemm<8><<<dim3(FIN / 64, 8), 256, 0, stream>>>(e, fw1, part, FIN, FIN);
    head_epilogue<8><<<(32 * FIN + 255) / 256, 256, 0, stream>>>(part, fb1, g1, FIN, 1);
    head_gemm<8><<<dim3(FHID / 64, 8), 256, 0, stream>>>(g1, fw2, part, FIN, FHID);
    head_epilogue<8><<<(32 * FHID + 255) / 256, 256, 0, stream>>>(part, fb2, g2, FHID, 1);
    head3<<<NOUT, 256, 0, stream>>>(g2, fw3, fb3, outp);
}